// Round 1
// baseline (6701.581 us; speedup 1.0000x reference)
//
#include <hip/hip_runtime.h>
#include <math.h>

#define HID 512
#define TENC 16384
#define NBLK 256
#define VOCAB 31
#define EOSI 29
#define MAXLEN 100
#define SCALE 0.044194173824159216f

// ws layout (4-byte units)
#define WS_GX    0          // 31*1536 floats
#define WS_GH    47616      // 1536
#define WS_H     49152      // 512
#define WS_SUM   49664      // 512
#define WS_PART  50176      // 512 (256 blocks * {max,expsum})
#define WS_BEST  50688      // int
#define WS_LEN   50689      // int
#define WS_CNT   50690      // 100 ints (per-step last-block tickets)

// d_out layout: [0..3099] logits, [3100] length (as float), [3101..] attn (100*16384)
#define OUT_LEN_IDX 3100
#define OUT_ATT_BASE 3101

static __device__ __forceinline__ float wsum(float v) {
#pragma unroll
  for (int m = 32; m >= 1; m >>= 1) v += __shfl_xor(v, m, 64);
  return v;
}
static __device__ __forceinline__ float sigm(float x) { return 1.0f / (1.0f + expf(-x)); }

__global__ __launch_bounds__(128) void k_init(float* ws) {
  int tid = threadIdx.x;
  for (int i = tid; i < HID; i += 128) ws[WS_H + i] = 0.0f;
  int* wi = (int*)ws;
  for (int i = tid; i < MAXLEN; i += 128) wi[WS_CNT + i] = 0;
  if (tid == 0) { wi[WS_BEST] = EOSI; wi[WS_LEN] = MAXLEN; }
}

// GX_all[v][r] = sum_d w_ih[r][d]*embed[v][d] + b_ih[r];  grid 384 x 256 (wave per row)
__global__ __launch_bounds__(256) void k_gx_all(const float* __restrict__ embed,
                                                const float* __restrict__ w_ih,
                                                const float* __restrict__ b_ih,
                                                float* __restrict__ ws) {
  int w = threadIdx.x >> 6, lane = threadIdx.x & 63;
  int r = blockIdx.x * 4 + w;  // 0..1535
  float wr[8];
  const float* wp = w_ih + (size_t)r * HID + lane * 8;
#pragma unroll
  for (int j = 0; j < 8; ++j) wr[j] = wp[j];
  float b = b_ih[r];
  for (int v = 0; v < VOCAB; ++v) {
    const float* e = embed + (size_t)v * HID + lane * 8;
    float d = 0.f;
#pragma unroll
    for (int j = 0; j < 8; ++j) d += wr[j] * e[j];
    d = wsum(d);
    if (lane == 0) ws[WS_GX + v * 1536 + r] = d + b;
  }
}

// gh = W_hh*h + b_hh ; block0 zeroes summary.  grid 192 x 256, 2 rows/wave
__global__ __launch_bounds__(256) void k_gh(const float* __restrict__ w_hh,
                                            const float* __restrict__ b_hh,
                                            float* __restrict__ ws) {
  int w = threadIdx.x >> 6, lane = threadIdx.x & 63;
#pragma unroll
  for (int rr = 0; rr < 2; ++rr) {
    int r = (blockIdx.x * 4 + w) * 2 + rr;
    const float* wp = w_hh + (size_t)r * HID + lane * 8;
    const float* hp = ws + WS_H + lane * 8;
    float d = 0.f;
#pragma unroll
    for (int j = 0; j < 8; ++j) d += wp[j] * hp[j];
    d = wsum(d);
    if (lane == 0) ws[WS_GH + r] = d + b_hh[r];
  }
  if (blockIdx.x == 0) {
    for (int i = threadIdx.x; i < HID; i += 256) ws[WS_SUM + i] = 0.0f;
  }
}

// per block: redundant h_new combine; 64 scores; raw scores -> d_out attn slot; partials
__global__ __launch_bounds__(256) void k_scores(const float* __restrict__ enc,
                                                float* __restrict__ ws,
                                                float* __restrict__ dout, int t) {
  __shared__ float hn[HID];
  __shared__ float sblk[64];
  int tid = threadIdx.x;
  const int* wi = (const int*)ws;
  const float* gx = ws + WS_GX + wi[WS_BEST] * 1536;
  const float* gh = ws + WS_GH;
  const float* h  = ws + WS_H;
  for (int i = tid; i < HID; i += 256) {
    float rg = sigm(gx[i] + gh[i]);
    float zg = sigm(gx[HID + i] + gh[HID + i]);
    float ng = tanhf(gx[2 * HID + i] + rg * gh[2 * HID + i]);
    hn[i] = (1.0f - zg) * ng + zg * h[i];
  }
  __syncthreads();
  int w = tid >> 6, lane = tid & 63;
  float hr[8];
#pragma unroll
  for (int j = 0; j < 8; ++j) hr[j] = hn[lane * 8 + j];
  float* att = dout + OUT_ATT_BASE + (size_t)t * TENC;
#pragma unroll 1
  for (int tt = 0; tt < 16; ++tt) {
    int trow = blockIdx.x * 64 + w * 16 + tt;
    const float4* kp = reinterpret_cast<const float4*>(enc + (size_t)trow * 1024 + lane * 8);
    float4 k0 = kp[0], k1 = kp[1];
    float d = hr[0]*k0.x + hr[1]*k0.y + hr[2]*k0.z + hr[3]*k0.w
            + hr[4]*k1.x + hr[5]*k1.y + hr[6]*k1.z + hr[7]*k1.w;
    bool okl = (k0.x!=30.f)||(k0.y!=30.f)||(k0.z!=30.f)||(k0.w!=30.f)
             ||(k1.x!=30.f)||(k1.y!=30.f)||(k1.z!=30.f)||(k1.w!=30.f);
    float s = wsum(d);
    bool ok = (__ballot(okl) != 0ull);
    s = ok ? s * SCALE : -1000000000.0f;
    if (lane == 0) { sblk[w * 16 + tt] = s; att[trow] = s; }
  }
  __syncthreads();
  if (tid < 64) {
    float m = sblk[tid];
    float bm = m;
#pragma unroll
    for (int msk = 32; msk >= 1; msk >>= 1) bm = fmaxf(bm, __shfl_xor(bm, msk, 64));
    float e = expf(m - bm);
    float bs = wsum(e);
    if (tid == 0) { ws[WS_PART + blockIdx.x * 2] = bm; ws[WS_PART + blockIdx.x * 2 + 1] = bs; }
  }
}

// per block: global (M,S); attn write; partial summary -> atomicAdd; last block: logits/argmax/state
__global__ __launch_bounds__(256) void k_attn(const float* __restrict__ enc,
                                              const float* __restrict__ w_out,
                                              const float* __restrict__ b_out,
                                              float* __restrict__ ws,
                                              float* __restrict__ dout, int t) {
  __shared__ float lsum[HID];
  __shared__ float wred[8];
  __shared__ float MS[2];
  __shared__ int islast;
  __shared__ float cvec[1024];
  __shared__ float lg[32];
  int tid = threadIdx.x, w = tid >> 6, lane = tid & 63;

  // global M,S from 256 partials
  float m = ws[WS_PART + tid * 2], s = ws[WS_PART + tid * 2 + 1];
#pragma unroll
  for (int msk = 32; msk >= 1; msk >>= 1) {
    float m2 = __shfl_xor(m, msk, 64), s2 = __shfl_xor(s, msk, 64);
    float M = fmaxf(m, m2);
    s = s * expf(m - M) + s2 * expf(m2 - M);
    m = M;
  }
  if (lane == 0) { wred[w * 2] = m; wred[w * 2 + 1] = s; }
  for (int i = tid; i < HID; i += 256) lsum[i] = 0.0f;
  __syncthreads();
  if (tid == 0) {
    float M = wred[0], S = wred[1];
#pragma unroll
    for (int k = 1; k < 4; ++k) {
      float m2 = wred[k * 2], s2 = wred[k * 2 + 1];
      float Mn = fmaxf(M, m2);
      S = S * expf(M - Mn) + s2 * expf(m2 - Mn);
      M = Mn;
    }
    MS[0] = M; MS[1] = 1.0f / S;
  }
  __syncthreads();
  float M = MS[0], invS = MS[1];
  float* att = dout + OUT_ATT_BASE + (size_t)t * TENC;
  float ps[8] = {0,0,0,0,0,0,0,0};
#pragma unroll 1
  for (int tt = 0; tt < 16; ++tt) {
    int trow = blockIdx.x * 64 + w * 16 + tt;
    float a = expf(att[trow] - M) * invS;
    if (lane == 0) att[trow] = a;
    const float4* vp = reinterpret_cast<const float4*>(enc + (size_t)trow * 1024 + 512 + lane * 8);
    float4 v0 = vp[0], v1 = vp[1];
    ps[0] += a * v0.x; ps[1] += a * v0.y; ps[2] += a * v0.z; ps[3] += a * v0.w;
    ps[4] += a * v1.x; ps[5] += a * v1.y; ps[6] += a * v1.z; ps[7] += a * v1.w;
  }
#pragma unroll
  for (int j = 0; j < 8; ++j) atomicAdd(&lsum[lane * 8 + j], ps[j]);
  __syncthreads();
  float* sum = ws + WS_SUM;
  for (int i = tid; i < HID; i += 256) atomicAdd(&sum[i], lsum[i]);
  __threadfence();
  __syncthreads();
  if (tid == 0) {
    int* cnt = (int*)ws + WS_CNT + t;
    int ticket = __hip_atomic_fetch_add(cnt, 1, __ATOMIC_ACQ_REL, __HIP_MEMORY_SCOPE_AGENT);
    islast = (ticket == NBLK - 1) ? 1 : 0;
  }
  __syncthreads();
  if (!islast) return;

  // ---- last block: logits, argmax, state update ----
  int* wi = (int*)ws;
  int bold = wi[WS_BEST];
  const float* gx = ws + WS_GX + bold * 1536;
  const float* gh = ws + WS_GH;
  const float* h  = ws + WS_H;
  for (int i = tid; i < HID; i += 256) {
    float rg = sigm(gx[i] + gh[i]);
    float zg = sigm(gx[HID + i] + gh[HID + i]);
    float ng = tanhf(gx[2 * HID + i] + rg * gh[2 * HID + i]);
    cvec[HID + i] = (1.0f - zg) * ng + zg * h[i];
    cvec[i] = __hip_atomic_load(&sum[i], __ATOMIC_RELAXED, __HIP_MEMORY_SCOPE_AGENT);
  }
  __syncthreads();
  int g = tid >> 3, k = tid & 7;
  if (g < VOCAB) {
    const float* wo = w_out + (size_t)g * 1024;
    float acc = 0.f;
    for (int d = k; d < 1024; d += 8) acc += cvec[d] * wo[d];
#pragma unroll
    for (int msk = 4; msk >= 1; msk >>= 1) acc += __shfl_xor(acc, msk, 64);
    if (k == 0) lg[g] = acc + b_out[g];
  }
  __syncthreads();
  float* hw = ws + WS_H;
  for (int i = tid; i < HID; i += 256) hw[i] = cvec[HID + i];
  if (tid < VOCAB) dout[(size_t)t * VOCAB + tid] = lg[tid];
  if (tid == 0) {
    int bb = 0; float bv = lg[0];
#pragma unroll
    for (int v = 1; v < VOCAB; ++v) { if (lg[v] > bv) { bv = lg[v]; bb = v; } }
    wi[WS_BEST] = bb;
    int L = wi[WS_LEN];
    if (bb == EOSI && t < L) { L = t; wi[WS_LEN] = L; }
    if (t == MAXLEN - 1) dout[OUT_LEN_IDX] = (float)L;
  }
}

extern "C" void kernel_launch(void* const* d_in, const int* in_sizes, int n_in,
                              void* d_out, int out_size, void* d_ws, size_t ws_size,
                              hipStream_t stream) {
  const float* enc   = (const float*)d_in[0];
  const float* embed = (const float*)d_in[2];
  const float* w_ih  = (const float*)d_in[3];
  const float* w_hh  = (const float*)d_in[4];
  const float* b_ih  = (const float*)d_in[5];
  const float* b_hh  = (const float*)d_in[6];
  const float* w_out = (const float*)d_in[7];
  const float* b_out = (const float*)d_in[8];
  float* dout = (float*)d_out;
  float* ws = (float*)d_ws;

  hipLaunchKernelGGL(k_init, dim3(1), dim3(128), 0, stream, ws);
  hipLaunchKernelGGL(k_gx_all, dim3(384), dim3(256), 0, stream, embed, w_ih, b_ih, ws);
  for (int t = 0; t < MAXLEN; ++t) {
    hipLaunchKernelGGL(k_gh, dim3(192), dim3(256), 0, stream, w_hh, b_hh, ws);
    hipLaunchKernelGGL(k_scores, dim3(NBLK), dim3(256), 0, stream, enc, ws, dout, t);
    hipLaunchKernelGGL(k_attn, dim3(NBLK), dim3(256), 0, stream, enc, w_out, b_out, ws, dout, t);
  }
}